// Round 1
// baseline (278.626 us; speedup 1.0000x reference)
//
#include <hip/hip_runtime.h>
#include <stdint.h>

#define D   64
#define L   50
#define NUM_U 30000
#define NUM_I 20000
#define PW2 296   // per-wave LDS dwords: dla 96 | escf/cat 192 | +8 align

// r3: floats are f32. r4: __shfl(ds_bpermute) latency-bound. r5: readlane->SGPR.
// r6: H precompute in ws. r7: Wg-MFMA epilogue (verified layouts). r8: all bulk
// math on MFMA: 245us, VALU 40% + MFMA 8% -> latency-bound, 4 blocks/CU.
// r9: LDS 36.4->30.9KB (5 blocks/CU), fuse 4 dispatches into 2. 241.5us.
// r10: attn = 144us, MfmaUtil 8 / VALU 42 / occ 53 -> still latency-bound.
//      Drop the LDS mailbox entirely (H is L2/L3-resident; staging was pure
//      overhead): scores-B = bpermute(nbr)+coalesced 16B global loads,
//      sums-B = coalesced u16 global loads, dh/lm copied as raw bf16.
//      LDS 31.6KB -> 4.7KB/block, launch_bounds(256,6). prep untouched
//      (isolating the ~97us non-attn residue for next round's top-5).

typedef __attribute__((ext_vector_type(8))) short short8x;   // 8 bf16
typedef __attribute__((ext_vector_type(4))) float f32x4;     // MFMA acc

__device__ __forceinline__ float lof(unsigned int u) {
    union { unsigned int i; float f; } v; v.i = u << 16; return v.f;
}
__device__ __forceinline__ float hif(unsigned int u) {
    union { unsigned int i; float f; } v; v.i = u & 0xffff0000u; return v.f;
}
__device__ __forceinline__ unsigned int f2bfbits(float f) {
    union { float f; unsigned int i; } v; v.f = f;
    return (v.i + 0x7fffu + ((v.i >> 16) & 1u)) >> 16;   // RNE
}
__device__ __forceinline__ unsigned int packbf(float a, float b) {
    return f2bfbits(a) | (f2bfbits(b) << 16);
}
__device__ __forceinline__ float rl(float v, int l) {
    return __int_as_float(__builtin_amdgcn_readlane(__float_as_int(v), l));
}
__device__ __forceinline__ int rli(int v, int l) {
    return __builtin_amdgcn_readlane(v, l);
}

// ---------------- K1: fused prep: H = feat@W  +  bf16 weight packing --------
__global__ __launch_bounds__(256) void prep(
    const float* __restrict__ user_feat, const float* __restrict__ item_feat,
    const float* __restrict__ W_u, const float* __restrict__ W_i,
    const float* __restrict__ Wg_i, const float* __restrict__ Wg_u,
    const float* __restrict__ te_i, const float* __restrict__ te_u,
    const float* __restrict__ tk_i, const float* __restrict__ tk_u,
    unsigned int* __restrict__ H,
    unsigned short* __restrict__ WgPi, unsigned short* __restrict__ WgPu,
    unsigned short* __restrict__ tePi, unsigned short* __restrict__ tePu,
    unsigned short* __restrict__ tkPi, unsigned short* __restrict__ tkPu)
{
    const int tid = threadIdx.x;
    if (blockIdx.x < 3125) {
        const int lane = tid & 63, wid = tid >> 6;
        int r0 = blockIdx.x * 16 + wid * 4;           // 30000%16==0: no straddle
        const float* src; const float* W;
        if (r0 < NUM_U) { src = user_feat + (size_t)r0 * D;            W = W_u; }
        else            { src = item_feat + (size_t)(r0 - NUM_U) * D;  W = W_i; }
        float f0 = src[0 * D + lane], f1 = src[1 * D + lane];
        float f2 = src[2 * D + lane], f3 = src[3 * D + lane];
        float a0 = 0.f, a1 = 0.f, a2 = 0.f, a3 = 0.f;
#pragma unroll
        for (int k = 0; k < 64; k++) {
            float wk = W[k * 64 + lane];
            a0 += rl(f0, k) * wk; a1 += rl(f1, k) * wk;
            a2 += rl(f2, k) * wk; a3 += rl(f3, k) * wk;
        }
        int li = (lane & 31) << 1;
        float p0 = __shfl(a0, li), q0 = __shfl(a0, li | 1);
        float p1 = __shfl(a1, li), q1 = __shfl(a1, li | 1);
        float p2 = __shfl(a2, li), q2 = __shfl(a2, li | 1);
        float p3 = __shfl(a3, li), q3 = __shfl(a3, li | 1);
        if (lane < 32) {
            H[(size_t)(r0 + 0) * 32 + lane] = packbf(p0, q0);
            H[(size_t)(r0 + 1) * 32 + lane] = packbf(p1, q1);
            H[(size_t)(r0 + 2) * 32 + lane] = packbf(p2, q2);
            H[(size_t)(r0 + 3) * 32 + lane] = packbf(p3, q3);
        }
    } else {
        int gid = (blockIdx.x - 3125) * 256 + tid;     // 16 blocks, gs=4096
        for (int idx = gid; idx < 8192; idx += 4096) {
            int n = idx >> 7, k = idx & 127;
            WgPi[idx] = (unsigned short)f2bfbits(Wg_i[k * 64 + n]);
            WgPu[idx] = (unsigned short)f2bfbits(Wg_u[k * 64 + n]);
        }
        {
            int idx = gid;                              // 4096 elements, 1 iter
            int r = idx >> 6, k = idx & 63;
            tePi[idx] = (r < L) ? (unsigned short)f2bfbits(te_i[r * 64 + k]) : 0;
            tePu[idx] = (r < L) ? (unsigned short)f2bfbits(te_u[r * 64 + k]) : 0;
            int d = idx >> 6, rr = idx & 63;
            tkPi[idx] = (rr < L) ? (unsigned short)f2bfbits(tk_i[rr * 64 + d]) : 0;
            tkPu[idx] = (rr < L) ? (unsigned short)f2bfbits(tk_u[rr * 64 + d]) : 0;
        }
    }
}

// ---------------- K2: fused attention, both sides, MFMA math ----------------
// r10: no LDS mailbox. H rows are read straight from global (L2/L3-resident):
//   scores B-frag  = 16B coalesced load at H[nbr[c16+16nt]] + d-offset
//   sums   B-frag  = 8x u16 loads H[nbr[k]][dcol] (32B-coalesced per quarter)
// LDS holds only the tiny per-wave scratch: dla (A-frags) + escf/cat overlay.
__global__ __launch_bounds__(256, 6) void attn_fused(
    const unsigned int* __restrict__ H,
    const float* __restrict__ user_feat, const float* __restrict__ item_feat,
    const unsigned short* __restrict__ WgPi, const unsigned short* __restrict__ WgPu,
    const unsigned short* __restrict__ tePi, const unsigned short* __restrict__ tePu,
    const unsigned short* __restrict__ tkPi, const unsigned short* __restrict__ tkPu,
    const int* __restrict__ item_nbr, const int* __restrict__ item_time,
    const int* __restrict__ user_nbr, const int* __restrict__ user_time,
    float* __restrict__ out)
{
    __shared__ unsigned int lds[4 * PW2];   // 4736 B

    const int tid = threadIdx.x, lane = tid & 63, wid = tid >> 6;
    const bool iside = blockIdx.x < (NUM_I / 4);
    const int bb = iside ? blockIdx.x : blockIdx.x - NUM_I / 4;
    const int n = bb * 4 + wid;
    const int src_base = iside ? 0 : NUM_U;
    const int dst_base = iside ? NUM_U : 0;
    const float* dst_feat = iside ? item_feat : user_feat;
    const unsigned short* WgP  = iside ? WgPi : WgPu;
    const unsigned short* teP  = iside ? tePi : tePu;
    const unsigned short* tekP = iside ? tkPi : tkPu;
    const int* nbr   = iside ? item_nbr  : user_nbr;
    const int* timev = iside ? item_time : user_time;
    float* outp = out + (iside ? (size_t)NUM_U * D : 0);

    const int q4 = lane >> 4, c16 = lane & 15;

    // u16 view of packed H: H_u16[node*64 + d] = bf16 of element d
    const unsigned short* Hs16 = (const unsigned short*)H + (size_t)src_base * 64;
    const unsigned short* Hd16 = (const unsigned short*)H + (size_t)dst_base * 64;

    // per-wave LDS slices (16B-aligned at their bases)
    unsigned int*   wld  = lds + wid * PW2;
    unsigned short* dla  = (unsigned short*)wld;          // 192 u16: dh|lm, overlay alpha|a1|beta
    float*          escf = (float*)(wld + 96);            // e|e1|teh (192 f32)
    unsigned short* cat  = (unsigned short*)(wld + 96);   // overlay: [hl|hs] bf16

    // ---- metadata ----
    int t   = (lane < L) ? timev[(size_t)n * L + lane] : 0;
    int nbv = (lane < L) ? nbr[(size_t)n * L + lane]  : 0;
    unsigned int key  = (lane < L) ? ((((unsigned)t) << 6) | (unsigned)lane) : 0u;
    unsigned int key2 = (lane < L) ? ((((unsigned)t) << 6) | (unsigned)(63 - lane)) : 0u;

    int rank = 0;
#pragma unroll
    for (int j = 0; j < L; j++) {
        unsigned int kj = (unsigned int)rli((int)key, j);
        rank += (kj < key) ? 1 : 0;
    }
    int re_o = (lane < L) ? (L - 1 - rank) : lane;   // pad lanes: distinct slots

    unsigned int m2 = key2;
#pragma unroll
    for (int s = 32; s; s >>= 1) { unsigned int o2 = __shfl_xor(m2, s); m2 = (o2 > m2) ? o2 : m2; }
    const int last = 63 - (int)(m2 & 63u);

    // ---- dh / lm: already bf16 inside H, copy u16 straight into A-frag rows
    dla[lane] = Hd16[(size_t)n * 64 + lane];
    int nbl = __shfl(nbv, last);                       // last is wave-uniform
    dla[64 + lane] = Hs16[(size_t)(unsigned)nbl * 64 + lane];

    // ---- neighbor row ids for the score tiles (n-index = c16 + 16*nt) ----
    int rowN[4];
#pragma unroll
    for (int nt = 0; nt < 4; nt++)
        rowN[nt] = __builtin_amdgcn_ds_bpermute((c16 + 16 * nt) << 2, nbv);

    // ---- scores + teh via MFMA: D=[dh;lm]·M^T, D_t=[dh]·te^T ----
    // rows >= L read garbage H rows (nbv pad = 0) — masked after, and their
    // alpha/a1/beta are exact zeros so the sums pass is unaffected.
    f32x4 zero4 = {0.f, 0.f, 0.f, 0.f};
    f32x4 acc_e[4], acc_t[4];
#pragma unroll
    for (int nt = 0; nt < 4; nt++) { acc_e[nt] = zero4; acc_t[nt] = zero4; }
#pragma unroll
    for (int kt = 0; kt < 2; kt++) {
        short8x afr = *(const short8x*)(dla + (c16 & 1) * 64 + kt * 32 + q4 * 8);
#pragma unroll
        for (int nt = 0; nt < 4; nt++) {
            int row = c16 + 16 * nt;
            short8x bv = *(const short8x*)(Hs16 + (unsigned)rowN[nt] * 64u
                                                + (unsigned)(kt * 32 + q4 * 8));
            acc_e[nt] = __builtin_amdgcn_mfma_f32_16x16x32_bf16(afr, bv, acc_e[nt], 0, 0, 0);
            short8x bt = *(const short8x*)(teP + row * 64 + kt * 32 + q4 * 8);
            acc_t[nt] = __builtin_amdgcn_mfma_f32_16x16x32_bf16(afr, bt, acc_t[nt], 0, 0, 0);
        }
    }
    if (q4 == 0) {
#pragma unroll
        for (int nt = 0; nt < 4; nt++) {
            escf[c16 + 16 * nt]       = acc_e[nt][0];   // e
            escf[64 + c16 + 16 * nt]  = acc_e[nt][1];   // e1
            escf[128 + c16 + 16 * nt] = acc_t[nt][0];   // teh (rank-indexed)
        }
    }
    float e  = escf[lane];
    float e1 = escf[64 + lane];
    float th = escf[128 + re_o];

    e = (e + th) * 0.125f;
    e1 *= 0.125f;
    if (lane >= L) { e = -3e38f; e1 = -3e38f; }

    // ---- dual softmax over neighbors ----
    float mx = e;
#pragma unroll
    for (int s = 32; s; s >>= 1) { float o2 = __shfl_xor(mx, s); mx = (o2 > mx) ? o2 : mx; }
    float ex = __expf(e - mx);
    float sm = ex;
#pragma unroll
    for (int s = 32; s; s >>= 1) sm += __shfl_xor(sm, s);
    float alpha = ex / sm;

    float mx1 = e1;
#pragma unroll
    for (int s = 32; s; s >>= 1) { float o2 = __shfl_xor(mx1, s); mx1 = (o2 > mx1) ? o2 : mx1; }
    float ex1 = __expf(e1 - mx1);
    float sm1 = ex1;
#pragma unroll
    for (int s = 32; s; s >>= 1) sm1 += __shfl_xor(sm1, s);
    float aw = ex1 / sm1;

    // ---- alpha/a1/beta (bf16) overlay onto dla (dh/lm dead after scores) ----
    dla[lane]       = (unsigned short)f2bfbits(alpha);
    dla[64 + lane]  = (unsigned short)f2bfbits(aw);
    dla[128 + re_o] = (unsigned short)f2bfbits(alpha);   // beta[r]: alpha at rank r

    // ---- sums via MFMA: [alpha;a1]·M (u16 gathers) + [beta]·tek^T ----
    f32x4 acc_s[4], acc_k[4];
#pragma unroll
    for (int nt = 0; nt < 4; nt++) { acc_s[nt] = zero4; acc_k[nt] = zero4; }
#pragma unroll
    for (int kt = 0; kt < 2; kt++) {
        short8x aS = *(const short8x*)(dla + (c16 & 1) * 64 + kt * 32 + q4 * 8);
        short8x aB = *(const short8x*)(dla + 128 + kt * 32 + q4 * 8);
        int ro[8];
#pragma unroll
        for (int i = 0; i < 8; i++)
            ro[i] = __builtin_amdgcn_ds_bpermute((kt * 32 + q4 * 8 + i) << 2, nbv);
#pragma unroll
        for (int nt = 0; nt < 4; nt++) {
            int dcol = c16 + 16 * nt;
            union { short8x v; unsigned short u[8]; } bu;
#pragma unroll
            for (int i = 0; i < 8; i++)
                bu.u[i] = Hs16[(unsigned)ro[i] * 64u + (unsigned)dcol];
            acc_s[nt] = __builtin_amdgcn_mfma_f32_16x16x32_bf16(aS, bu.v, acc_s[nt], 0, 0, 0);
            short8x bK = *(const short8x*)(tekP + dcol * 64 + kt * 32 + q4 * 8);
            acc_k[nt] = __builtin_amdgcn_mfma_f32_16x16x32_bf16(aB, bK, acc_k[nt], 0, 0, 0);
        }
    }
    // cat = [hl|hs] overlay onto escf (dead after softmax)
    if (q4 == 0) {
#pragma unroll
        for (int nt = 0; nt < 4; nt++) {
            cat[c16 + 16 * nt]      = (unsigned short)f2bfbits(acc_s[nt][0] + acc_k[nt][0]);
            cat[64 + c16 + 16 * nt] = (unsigned short)f2bfbits(acc_s[nt][1]);
        }
    }
    __syncthreads();   // only barrier: epilogue mixes waves' cat rows

    // ---- epilogue: out = elu(cat @ Wg + f) ----
    short8x bfr[4];
#pragma unroll
    for (int tK = 0; tK < 4; tK++)
        bfr[tK] = *(const short8x*)(WgP + (wid * 16 + c16) * 128 + tK * 32 + q4 * 8);

    const unsigned short* catw = (const unsigned short*)(lds + (lane & 3) * PW2 + 96);
    f32x4 acc = zero4;
#pragma unroll
    for (int tK = 0; tK < 4; tK++) {
        short8x a = *(const short8x*)(catw + tK * 32 + q4 * 8);
        acc = __builtin_amdgcn_mfma_f32_16x16x32_bf16(a, bfr[tK], acc, 0, 0, 0);
    }
    float r01 = (q4 & 1) ? acc[1] : acc[0];
    float r23 = (q4 & 1) ? acc[3] : acc[2];
    float pv  = (q4 & 2) ? r23 : r01;

    int node = bb * 4 + q4;
    float fres = dst_feat[(size_t)node * D + wid * 16 + c16];
    float oo = pv + fres;
    oo = (oo > 0.f) ? oo : (__expf(oo) - 1.f);
    outp[(size_t)node * D + wid * 16 + c16] = oo;
}

// ---------------- fallback: round-5 monolith (passed, 447us) ---------------
__global__ __launch_bounds__(256) void attn_mono(
    const float* __restrict__ src_feat, const float* __restrict__ dst_feat,
    const float* __restrict__ W_src, const float* __restrict__ W_dst,
    const float* __restrict__ Wg, const float* __restrict__ te,
    const float* __restrict__ tek, const int* __restrict__ nbr,
    const int* __restrict__ timev, float* __restrict__ out)
{
    __shared__ unsigned int ws32[64 * 33];
    __shared__ unsigned int te32[L * 33];
    __shared__ unsigned int mbs[4][L * 33];
    const int tid = threadIdx.x, lane = tid & 63, wid = tid >> 6;
    const int n = blockIdx.x * 4 + wid;
    {
        const float2* Wf2 = (const float2*)W_src;
        const float2* Te2 = (const float2*)te;
        for (int idx = tid; idx < 2048; idx += 256) {
            float2 w = Wf2[idx];
            ws32[(idx >> 5) * 33 + (idx & 31)] = packbf(w.x, w.y);
            if (idx < 1600) {
                float2 t2 = Te2[idx];
                te32[(idx >> 5) * 33 + (idx & 31)] = packbf(t2.x, t2.y);
            }
        }
    }
    __syncthreads();
    int t  = (lane < L) ? timev[(size_t)n * L + lane] : 0;
    int nb = (lane < L) ? nbr[(size_t)n * L + lane]  : 0;
    unsigned int key  = (lane < L) ? ((((unsigned)t) << 6) | (unsigned)lane) : 0u;
    unsigned int key2 = (lane < L) ? ((((unsigned)t) << 6) | (unsigned)(63 - lane)) : 0u;
    int rank = 0;
#pragma unroll
    for (int j = 0; j < L; j++) {
        unsigned int kj = (unsigned int)rli((int)key, j);
        rank += (kj < key) ? 1 : 0;
    }
    int re_o = (lane < L) ? (L - 1 - rank) : 0;
    unsigned int m2 = key2;
#pragma unroll
    for (int s = 32; s; s >>= 1) { unsigned int o2 = __shfl_xor(m2, s); m2 = (o2 > m2) ? o2 : m2; }
    const int last = 63 - (int)(m2 & 63u);
    const int rr = (lane < L) ? lane : (L - 1);
    float f = dst_feat[(size_t)n * D + lane];
    float dh;
    {
        float b0 = 0.f, b1 = 0.f, b2 = 0.f, b3 = 0.f;
#pragma unroll
        for (int k = 0; k < 64; k += 4) {
            b0 += rl(f, k + 0) * W_dst[(k + 0) * 64 + lane];
            b1 += rl(f, k + 1) * W_dst[(k + 1) * 64 + lane];
            b2 += rl(f, k + 2) * W_dst[(k + 2) * 64 + lane];
            b3 += rl(f, k + 3) * W_dst[(k + 3) * 64 + lane];
        }
        dh = (b0 + b1) + (b2 + b3);
    }
    float v1;
    {
        float b0 = 0.f, b1 = 0.f, b2 = 0.f, b3 = 0.f;
#pragma unroll
        for (int j = 0; j < 32; j += 2) {
            unsigned int u0 = ws32[lane * 33 + j];
            unsigned int u1 = ws32[lane * 33 + j + 1];
            b0 += lof(u0) * rl(dh, 2 * j + 0);
            b1 += hif(u0) * rl(dh, 2 * j + 1);
            b2 += lof(u1) * rl(dh, 2 * j + 2);
            b3 += hif(u1) * rl(dh, 2 * j + 3);
        }
        v1 = (b0 + b1) + (b2 + b3);
    }
    unsigned int* mbw = mbs[wid];
    {
        const float2* src2 = (const float2*)src_feat;
        int half = lane >> 5, col = lane & 31;
#pragma unroll
        for (int l = 0; l < L; l += 2) {
            int ra = rli(nb, l), rb = rli(nb, l + 1);
            int r = half ? rb : ra;
            float2 v = src2[(size_t)r * 32 + col];
            mbw[(l + half) * 33 + col] = packbf(v.x, v.y);
        }
    }
    __syncthreads();
    unsigned int ul = mbw[last * 33 + (lane >> 1)];
    float rlast = (lane & 1) ? hif(ul) : lof(ul);
    float g;
    {
        float b0 = 0.f, b1 = 0.f, b2 = 0.f, b3 = 0.f;
#pragma unroll
        for (int k = 0; k < 64; k += 4) {
            b0 += rl(rlast, k + 0) * W_src[(k + 0) * 64 + lane];
            b1 += rl(rlast, k + 1) * W_src[(k + 1) * 64 + lane];
            b2 += rl(rlast, k + 2) * W_src[(k + 2) * 64 + lane];
            b3 += rl(rlast, k + 3) * W_src[(k + 3) * 64 + lane];
        }
        g = (b0 + b1) + (b2 + b3);
    }
    float v2;
    {
        float b0 = 0.f, b1 = 0.f, b2 = 0.f, b3 = 0.f;
#pragma unroll
        for (int j = 0; j < 32; j += 2) {
            unsigned int u0 = ws32[lane * 33 + j];
            unsigned int u1 = ws32[lane * 33 + j + 1];
            b0 += lof(u0) * rl(g, 2 * j + 0);
            b1 += hif(u0) * rl(g, 2 * j + 1);
            b2 += lof(u1) * rl(g, 2 * j + 2);
            b3 += hif(u1) * rl(g, 2 * j + 3);
        }
        v2 = (b0 + b1) + (b2 + b3);
    }
    float teh;
    {
        float b0 = 0.f, b1 = 0.f, b2 = 0.f, b3 = 0.f;
#pragma unroll
        for (int j = 0; j < 32; j += 2) {
            unsigned int u0 = te32[rr * 33 + j];
            unsigned int u1 = te32[rr * 33 + j + 1];
            b0 += lof(u0) * rl(dh, 2 * j + 0);
            b1 += hif(u0) * rl(dh, 2 * j + 1);
            b2 += lof(u1) * rl(dh, 2 * j + 2);
            b3 += hif(u1) * rl(dh, 2 * j + 3);
        }
        teh = (b0 + b1) + (b2 + b3);
    }
    float e, e1;
    {
        float ea = 0.f, eb = 0.f, qa = 0.f, qb = 0.f;
#pragma unroll
        for (int j = 0; j < 32; j += 2) {
            unsigned int u0 = mbw[rr * 33 + j];
            unsigned int u1 = mbw[rr * 33 + j + 1];
            float m0 = lof(u0), m1 = hif(u0), m2f = lof(u1), m3 = hif(u1);
            ea += m0 * rl(v1, 2 * j + 0) + m1 * rl(v1, 2 * j + 1);
            eb += m2f * rl(v1, 2 * j + 2) + m3 * rl(v1, 2 * j + 3);
            qa += m0 * rl(v2, 2 * j + 0) + m1 * rl(v2, 2 * j + 1);
            qb += m2f * rl(v2, 2 * j + 2) + m3 * rl(v2, 2 * j + 3);
        }
        e = ea + eb; e1 = qa + qb;
    }
    e = (e + __shfl(teh, re_o)) * 0.125f;
    e1 *= 0.125f;
    if (lane >= L) { e = -3e38f; e1 = -3e38f; }
    float mx = e;
#pragma unroll
    for (int s = 32; s; s >>= 1) { float o2 = __shfl_xor(mx, s); mx = (o2 > mx) ? o2 : mx; }
    float ex = __expf(e - mx);
    float sm = ex;
#pragma unroll
    for (int s = 32; s; s >>= 1) sm += __shfl_xor(sm, s);
    float alpha = ex / sm;
    float mx1 = e1;
#pragma unroll
    for (int s = 32; s; s >>= 1) { float o2 = __shfl_xor(mx1, s); mx1 = (o2 > mx1) ? o2 : mx1; }
    float ex1 = __expf(e1 - mx1);
    float sm1 = ex1;
#pragma unroll
    for (int s = 32; s; s >>= 1) sm1 += __shfl_xor(sm1, s);
    float aw = ex1 / sm1;
    float sl, ss, tacc;
    {
        float sA = 0.f, sB = 0.f, hA = 0.f, hB = 0.f, tA = 0.f, tB = 0.f;
        int hcol = lane >> 1, odd = lane & 1;
#pragma unroll
        for (int l = 0; l < L; l += 2) {
            float saA = rl(alpha, l),     s1A = rl(aw, l);
            float saB = rl(alpha, l + 1), s1B = rl(aw, l + 1);
            int   roA = rli(re_o, l),     roB = rli(re_o, l + 1);
            unsigned int uA = mbw[(l + 0) * 33 + hcol];
            unsigned int uB = mbw[(l + 1) * 33 + hcol];
            float mA = odd ? hif(uA) : lof(uA);
            float mB = odd ? hif(uB) : lof(uB);
            sA += saA * mA; hA += s1A * mA; tA += saA * tek[roA * 64 + lane];
            sB += saB * mB; hB += s1B * mB; tB += saB * tek[roB * 64 + lane];
        }
        sl = sA + sB; ss = hA + hB; tacc = tA + tB;
    }
    float hl, hs;
    {
        float lA = 0.f, lB = 0.f, sA = 0.f, sB = 0.f;
#pragma unroll
        for (int k = 0; k < 64; k += 2) {
            float w0 = W_src[(k + 0) * 64 + lane];
            float w1 = W_src[(k + 1) * 64 + lane];
            lA += rl(sl, k + 0) * w0; sA += rl(ss, k + 0) * w0;
            lB += rl(sl, k + 1) * w1; sB += rl(ss, k + 1) * w1;
        }
        hl = tacc + lA + lB; hs = sA + sB;
    }
    float o;
    {
        float o0 = 0.f, o1 = 0.f, o2 = 0.f, o3 = 0.f;
#pragma unroll
        for (int k = 0; k < 64; k += 2) {
            o0 += rl(hl, k + 0) * Wg[(k + 0) * 64 + lane];
            o1 += rl(hl, k + 1) * Wg[(k + 1) * 64 + lane];
            o2 += rl(hs, k + 0) * Wg[(k + 64) * 64 + lane];
            o3 += rl(hs, k + 1) * Wg[(k + 65) * 64 + lane];
        }
        o = f + (o0 + o1) + (o2 + o3);
    }
    o = (o > 0.f) ? o : (__expf(o) - 1.f);
    out[(size_t)n * D + lane] = o;
}

extern "C" void kernel_launch(void* const* d_in, const int* in_sizes, int n_in,
                              void* d_out, int out_size, void* d_ws, size_t ws_size,
                              hipStream_t stream) {
    const float* user_feat = (const float*)d_in[0];
    const float* item_feat = (const float*)d_in[1];
    const float* W_u  = (const float*)d_in[2];
    const float* W_i  = (const float*)d_in[3];
    const float* Wg_u = (const float*)d_in[4];
    const float* Wg_i = (const float*)d_in[5];
    const float* i_te   = (const float*)d_in[6];
    const float* i_te_k = (const float*)d_in[7];
    const float* u_te   = (const float*)d_in[8];
    const float* u_te_k = (const float*)d_in[9];
    const int* item_nbr  = (const int*)d_in[10];
    const int* item_time = (const int*)d_in[11];
    const int* user_nbr  = (const int*)d_in[12];
    const int* user_time = (const int*)d_in[13];
    (void)in_sizes; (void)n_in; (void)out_size;

    float* outp = (float*)d_out;
    const size_t H_BYTES = (size_t)(NUM_U + NUM_I) * 32 * 4;            // 6.4 MB
    const size_t NEED = H_BYTES + 2 * 16384 + 4 * 8192;                 // +64 KB aux

    if (ws_size >= NEED) {
        unsigned int* Hp = (unsigned int*)d_ws;
        unsigned char* aux = (unsigned char*)d_ws + H_BYTES;
        unsigned short* WgPi = (unsigned short*)(aux);
        unsigned short* WgPu = (unsigned short*)(aux + 16384);
        unsigned short* tePi = (unsigned short*)(aux + 32768);
        unsigned short* tePu = (unsigned short*)(aux + 40960);
        unsigned short* tkPi = (unsigned short*)(aux + 49152);
        unsigned short* tkPu = (unsigned short*)(aux + 57344);

        prep<<<3141, 256, 0, stream>>>(user_feat, item_feat, W_u, W_i,
                                       Wg_i, Wg_u, i_te, u_te, i_te_k, u_te_k,
                                       Hp, WgPi, WgPu, tePi, tePu, tkPi, tkPu);
        attn_fused<<<(NUM_I + NUM_U) / 4, 256, 0, stream>>>(
            Hp, user_feat, item_feat, WgPi, WgPu, tePi, tePu, tkPi, tkPu,
            item_nbr, item_time, user_nbr, user_time, outp);
    } else {
        attn_mono<<<NUM_I / 4, 256, 0, stream>>>(
            user_feat, item_feat, W_u, W_i, Wg_i, i_te, i_te_k,
            item_nbr, item_time, outp + (size_t)NUM_U * D);
        attn_mono<<<NUM_U / 4, 256, 0, stream>>>(
            item_feat, user_feat, W_i, W_u, Wg_u, u_te, u_te_k,
            user_nbr, user_time, outp);
    }
}

// Round 2
// 236.115 us; speedup vs baseline: 1.1800x; 1.1800x over previous
//
#include <hip/hip_runtime.h>
#include <stdint.h>

#define D   64
#define L   50
#define NUM_U 30000
#define NUM_I 20000
#define MROWS 50
#define PW3 (MROWS * 32 + 96 + 192)   // mailbox 1600 dw | dla 96 | escf 192 = 1888 dw

// r8: all bulk math on MFMA: 245us. r9: LDS 30.9KB, 2 dispatches: 241.5us,
//     attn=144us VALU42/Mfma8/occ53 -> VALU-issue + gather-drain bound.
// r10: dropped LDS mailbox, global gathers: 186us REGRESSED (VALU 23%,
//     L2-gather latency on critical path). Mailbox locality is load-bearing.
// r11: keep r9 mailbox, cut its FILL cost: global_load_lds width=16 (6 instrs
//     for 48 rows + 1 manual pass for rows 48..49), linear stride-32 rows with
//     16B-chunk XOR swizzle (chunk ^= row&7) via pre-swizzled global source
//     (source perm == read perm). Scores: one ds_read_b128/tile. Sums: swizzled
//     u16 gathers. dh/lm as raw bf16 from H (bit-identical). setprio around
//     MFMA clusters. Rows >=50 never read (alpha/beta exactly 0 there).

typedef __attribute__((ext_vector_type(8))) short short8x;   // 8 bf16
typedef __attribute__((ext_vector_type(4))) float f32x4;     // MFMA acc

__device__ __forceinline__ float lof(unsigned int u) {
    union { unsigned int i; float f; } v; v.i = u << 16; return v.f;
}
__device__ __forceinline__ float hif(unsigned int u) {
    union { unsigned int i; float f; } v; v.i = u & 0xffff0000u; return v.f;
}
__device__ __forceinline__ unsigned int f2bfbits(float f) {
    union { float f; unsigned int i; } v; v.f = f;
    return (v.i + 0x7fffu + ((v.i >> 16) & 1u)) >> 16;   // RNE
}
__device__ __forceinline__ unsigned int packbf(float a, float b) {
    return f2bfbits(a) | (f2bfbits(b) << 16);
}
__device__ __forceinline__ float rl(float v, int l) {
    return __int_as_float(__builtin_amdgcn_readlane(__float_as_int(v), l));
}
__device__ __forceinline__ int rli(int v, int l) {
    return __builtin_amdgcn_readlane(v, l);
}
__device__ __forceinline__ void gload_lds16(const void* g, void* l) {
    __builtin_amdgcn_global_load_lds(
        (const __attribute__((address_space(1))) unsigned int*)g,
        (__attribute__((address_space(3))) unsigned int*)l, 16, 0, 0);
}

// ---------------- K1: fused prep: H = feat@W  +  bf16 weight packing --------
__global__ __launch_bounds__(256) void prep(
    const float* __restrict__ user_feat, const float* __restrict__ item_feat,
    const float* __restrict__ W_u, const float* __restrict__ W_i,
    const float* __restrict__ Wg_i, const float* __restrict__ Wg_u,
    const float* __restrict__ te_i, const float* __restrict__ te_u,
    const float* __restrict__ tk_i, const float* __restrict__ tk_u,
    unsigned int* __restrict__ H,
    unsigned short* __restrict__ WgPi, unsigned short* __restrict__ WgPu,
    unsigned short* __restrict__ tePi, unsigned short* __restrict__ tePu,
    unsigned short* __restrict__ tkPi, unsigned short* __restrict__ tkPu)
{
    const int tid = threadIdx.x;
    if (blockIdx.x < 3125) {
        const int lane = tid & 63, wid = tid >> 6;
        int r0 = blockIdx.x * 16 + wid * 4;           // 30000%16==0: no straddle
        const float* src; const float* W;
        if (r0 < NUM_U) { src = user_feat + (size_t)r0 * D;            W = W_u; }
        else            { src = item_feat + (size_t)(r0 - NUM_U) * D;  W = W_i; }
        float f0 = src[0 * D + lane], f1 = src[1 * D + lane];
        float f2 = src[2 * D + lane], f3 = src[3 * D + lane];
        float a0 = 0.f, a1 = 0.f, a2 = 0.f, a3 = 0.f;
#pragma unroll
        for (int k = 0; k < 64; k++) {
            float wk = W[k * 64 + lane];
            a0 += rl(f0, k) * wk; a1 += rl(f1, k) * wk;
            a2 += rl(f2, k) * wk; a3 += rl(f3, k) * wk;
        }
        int li = (lane & 31) << 1;
        float p0 = __shfl(a0, li), q0 = __shfl(a0, li | 1);
        float p1 = __shfl(a1, li), q1 = __shfl(a1, li | 1);
        float p2 = __shfl(a2, li), q2 = __shfl(a2, li | 1);
        float p3 = __shfl(a3, li), q3 = __shfl(a3, li | 1);
        if (lane < 32) {
            H[(size_t)(r0 + 0) * 32 + lane] = packbf(p0, q0);
            H[(size_t)(r0 + 1) * 32 + lane] = packbf(p1, q1);
            H[(size_t)(r0 + 2) * 32 + lane] = packbf(p2, q2);
            H[(size_t)(r0 + 3) * 32 + lane] = packbf(p3, q3);
        }
    } else {
        int gid = (blockIdx.x - 3125) * 256 + tid;     // 16 blocks, gs=4096
        for (int idx = gid; idx < 8192; idx += 4096) {
            int n = idx >> 7, k = idx & 127;
            WgPi[idx] = (unsigned short)f2bfbits(Wg_i[k * 64 + n]);
            WgPu[idx] = (unsigned short)f2bfbits(Wg_u[k * 64 + n]);
        }
        {
            int idx = gid;                              // 4096 elements, 1 iter
            int r = idx >> 6, k = idx & 63;
            tePi[idx] = (r < L) ? (unsigned short)f2bfbits(te_i[r * 64 + k]) : 0;
            tePu[idx] = (r < L) ? (unsigned short)f2bfbits(te_u[r * 64 + k]) : 0;
            int d = idx >> 6, rr = idx & 63;
            tkPi[idx] = (rr < L) ? (unsigned short)f2bfbits(tk_i[rr * 64 + d]) : 0;
            tkPu[idx] = (rr < L) ? (unsigned short)f2bfbits(tk_u[rr * 64 + d]) : 0;
        }
    }
}

// ---------------- K2: fused attention, both sides, MFMA math ----------------
__global__ __launch_bounds__(256, 5) void attn_fused(
    const unsigned int* __restrict__ H,
    const float* __restrict__ user_feat, const float* __restrict__ item_feat,
    const unsigned short* __restrict__ WgPi, const unsigned short* __restrict__ WgPu,
    const unsigned short* __restrict__ tePi, const unsigned short* __restrict__ tePu,
    const unsigned short* __restrict__ tkPi, const unsigned short* __restrict__ tkPu,
    const int* __restrict__ item_nbr, const int* __restrict__ item_time,
    const int* __restrict__ user_nbr, const int* __restrict__ user_time,
    float* __restrict__ out)
{
    __shared__ unsigned int lds[4 * PW3];   // 30208 B -> 5 blocks/CU

    const int tid = threadIdx.x, lane = tid & 63, wid = tid >> 6;
    const bool iside = blockIdx.x < (NUM_I / 4);
    const int bb = iside ? blockIdx.x : blockIdx.x - NUM_I / 4;
    const int n = bb * 4 + wid;
    const int src_base = iside ? 0 : NUM_U;
    const int dst_base = iside ? NUM_U : 0;
    const float* dst_feat = iside ? item_feat : user_feat;
    const unsigned short* WgP  = iside ? WgPi : WgPu;
    const unsigned short* teP  = iside ? tePi : tePu;
    const unsigned short* tekP = iside ? tkPi : tkPu;
    const int* nbr   = iside ? item_nbr  : user_nbr;
    const int* timev = iside ? item_time : user_time;
    float* outp = out + (iside ? (size_t)NUM_U * D : 0);

    const int q4 = lane >> 4, c16 = lane & 15;

    const unsigned int*   Hsrc = H + (size_t)src_base * 32;
    const unsigned short* Hs16 = (const unsigned short*)H + (size_t)src_base * 64;
    const unsigned short* Hd16 = (const unsigned short*)H + (size_t)dst_base * 64;

    // per-wave LDS slices
    unsigned int*   wld  = lds + wid * PW3;
    unsigned int*   mbw  = wld;                               // 50 rows x 32 dw, chunk-swizzled
    unsigned short* dla  = (unsigned short*)(wld + MROWS * 32);   // dh|lm, overlay alpha|a1|beta
    float*          escf = (float*)(wld + MROWS * 32 + 96);       // e|e1|teh (192 f32)
    unsigned short* cat  = (unsigned short*)(wld + MROWS * 32 + 96); // overlay [hl|hs]

    // ---- metadata ----
    int t   = (lane < L) ? timev[(size_t)n * L + lane] : 0;
    int nbv = (lane < L) ? nbr[(size_t)n * L + lane]  : 0;

    // ---- mailbox fill: rows 0..47 via global_load_lds (16B/lane, 8 rows/instr)
    // LDS[row][chunk c] = global[row][c ^ (row&7)]; row&7 == lane>>3 for all g
    {
        const int soff = (((lane & 7) ^ (lane >> 3)) << 4);   // swizzled src byte off
        const int rsel = (lane >> 3) << 2;                    // bpermute byte idx
#pragma unroll
        for (int g = 0; g < 6; g++) {
            int nb = __builtin_amdgcn_ds_bpermute(rsel + (g << 5), nbv);
            const char* gp = (const char*)(Hsrc + (size_t)(unsigned)nb * 32) + soff;
            gload_lds16(gp, (char*)mbw + (g << 10));
        }
        // rows 48..49: one manual pass (2 rows x 32 dw over 64 lanes)
        int row = 48 + (lane >> 5), d = lane & 31;
        int nb = __builtin_amdgcn_ds_bpermute(row << 2, nbv);
        unsigned int v = Hsrc[(size_t)(unsigned)nb * 32 + d];
        mbw[(row << 5) + ((((d >> 2) ^ (row & 7)) << 2) | (d & 3))] = v;
    }

    // ---- rank / last while DMA is in flight ----
    unsigned int key  = (lane < L) ? ((((unsigned)t) << 6) | (unsigned)lane) : 0u;
    unsigned int key2 = (lane < L) ? ((((unsigned)t) << 6) | (unsigned)(63 - lane)) : 0u;
    int rank = 0;
#pragma unroll
    for (int j = 0; j < L; j++) {
        unsigned int kj = (unsigned int)rli((int)key, j);
        rank += (kj < key) ? 1 : 0;
    }
    int re_o = (lane < L) ? (L - 1 - rank) : lane;   // pad lanes: distinct slots

    unsigned int m2 = key2;
#pragma unroll
    for (int s = 32; s; s >>= 1) { unsigned int o2 = __shfl_xor(m2, s); m2 = (o2 > m2) ? o2 : m2; }
    const int last = 63 - (int)(m2 & 63u);

    // ---- dh / lm: raw bf16 straight from H (bit-identical to f32 roundtrip)
    dla[lane] = Hd16[(size_t)n * 64 + lane];
    int nbl = __shfl(nbv, last);                      // last is wave-uniform
    dla[64 + lane] = Hs16[(size_t)(unsigned)nbl * 64 + lane];

    // ---- scores + teh via MFMA: D=[dh;lm]·M^T, D_t=[dh]·te^T ----
    f32x4 zero4 = {0.f, 0.f, 0.f, 0.f};
    f32x4 acc_e[4], acc_t[4];
#pragma unroll
    for (int nt = 0; nt < 4; nt++) { acc_e[nt] = zero4; acc_t[nt] = zero4; }
    __builtin_amdgcn_s_setprio(1);
#pragma unroll
    for (int kt = 0; kt < 2; kt++) {
        short8x afr = *(const short8x*)(dla + (c16 & 1) * 64 + kt * 32 + q4 * 8);
        int cc = kt * 4 + q4;                          // 16B chunk within row
#pragma unroll
        for (int nt = 0; nt < 4; nt++) {
            int row = c16 + 16 * nt;
            int rowc = (row < MROWS) ? row : 0;        // rows >=50 masked later
            short8x bv = *(const short8x*)((const char*)mbw + rowc * 128
                                           + ((cc ^ (rowc & 7)) << 4));
            acc_e[nt] = __builtin_amdgcn_mfma_f32_16x16x32_bf16(afr, bv, acc_e[nt], 0, 0, 0);
            short8x bt = *(const short8x*)(teP + row * 64 + kt * 32 + q4 * 8);
            acc_t[nt] = __builtin_amdgcn_mfma_f32_16x16x32_bf16(afr, bt, acc_t[nt], 0, 0, 0);
        }
    }
    __builtin_amdgcn_s_setprio(0);
    if (q4 == 0) {
#pragma unroll
        for (int nt = 0; nt < 4; nt++) {
            escf[c16 + 16 * nt]       = acc_e[nt][0];   // e
            escf[64 + c16 + 16 * nt]  = acc_e[nt][1];   // e1
            escf[128 + c16 + 16 * nt] = acc_t[nt][0];   // teh (rank-indexed)
        }
    }
    float e  = escf[lane];
    float e1 = escf[64 + lane];
    float th = escf[128 + re_o];

    e = (e + th) * 0.125f;
    e1 *= 0.125f;
    if (lane >= L) { e = -3e38f; e1 = -3e38f; }

    // ---- dual softmax over neighbors ----
    float mx = e;
#pragma unroll
    for (int s = 32; s; s >>= 1) { float o2 = __shfl_xor(mx, s); mx = (o2 > mx) ? o2 : mx; }
    float ex = __expf(e - mx);
    float sm = ex;
#pragma unroll
    for (int s = 32; s; s >>= 1) sm += __shfl_xor(sm, s);
    float alpha = ex / sm;

    float mx1 = e1;
#pragma unroll
    for (int s = 32; s; s >>= 1) { float o2 = __shfl_xor(mx1, s); mx1 = (o2 > mx1) ? o2 : mx1; }
    float ex1 = __expf(e1 - mx1);
    float sm1 = ex1;
#pragma unroll
    for (int s = 32; s; s >>= 1) sm1 += __shfl_xor(sm1, s);
    float aw = ex1 / sm1;

    // ---- alpha/a1/beta (bf16) overlay onto dla (dh/lm dead after scores) ----
    // pad lanes: alpha == aw == 0 exactly -> rows >=50 contribute nothing below
    dla[lane]       = (unsigned short)f2bfbits(alpha);
    dla[64 + lane]  = (unsigned short)f2bfbits(aw);
    dla[128 + re_o] = (unsigned short)f2bfbits(alpha);   // beta[r]: alpha at rank r

    // ---- sums via MFMA: [alpha;a1]·M (swizzled u16 col-reads) + [beta]·tek^T
    f32x4 acc_s[4], acc_k[4];
#pragma unroll
    for (int nt = 0; nt < 4; nt++) { acc_s[nt] = zero4; acc_k[nt] = zero4; }
    __builtin_amdgcn_s_setprio(1);
#pragma unroll
    for (int kt = 0; kt < 2; kt++) {
        short8x aS = *(const short8x*)(dla + (c16 & 1) * 64 + kt * 32 + q4 * 8);
        short8x aB = *(const short8x*)(dla + 128 + kt * 32 + q4 * 8);
        int kr128[8];
#pragma unroll
        for (int i = 0; i < 8; i++) {
            int k = kt * 32 + q4 * 8 + i;
            if (kt) k = (k < MROWS) ? k : (k - 32);   // alpha=0 rows: any finite row
            kr128[i] = k << 7;                        // preserves k&7 == i
        }
#pragma unroll
        for (int nt = 0; nt < 4; nt++) {
            int dc = c16 + 16 * nt;
            int t3 = dc >> 3;
            const char* cbase = (const char*)mbw + ((dc & 7) << 1);
            union { short8x v; unsigned short u[8]; } bu;
#pragma unroll
            for (int i = 0; i < 8; i++)
                bu.u[i] = *(const unsigned short*)(cbase + kr128[i] + ((t3 ^ i) << 4));
            acc_s[nt] = __builtin_amdgcn_mfma_f32_16x16x32_bf16(aS, bu.v, acc_s[nt], 0, 0, 0);
            short8x bK = *(const short8x*)(tekP + dc * 64 + kt * 32 + q4 * 8);
            acc_k[nt] = __builtin_amdgcn_mfma_f32_16x16x32_bf16(aB, bK, acc_k[nt], 0, 0, 0);
        }
    }
    __builtin_amdgcn_s_setprio(0);
    // cat = [hl|hs] overlay onto escf (dead after softmax)
    if (q4 == 0) {
#pragma unroll
        for (int nt = 0; nt < 4; nt++) {
            cat[c16 + 16 * nt]      = (unsigned short)f2bfbits(acc_s[nt][0] + acc_k[nt][0]);
            cat[64 + c16 + 16 * nt] = (unsigned short)f2bfbits(acc_s[nt][1]);
        }
    }
    __syncthreads();   // only barrier: epilogue mixes waves' cat rows

    // ---- epilogue: out = elu(cat @ Wg + f) ----
    short8x bfr[4];
#pragma unroll
    for (int tK = 0; tK < 4; tK++)
        bfr[tK] = *(const short8x*)(WgP + (wid * 16 + c16) * 128 + tK * 32 + q4 * 8);

    const unsigned short* catw =
        (const unsigned short*)(lds + (lane & 3) * PW3 + MROWS * 32 + 96);
    f32x4 acc = zero4;
#pragma unroll
    for (int tK = 0; tK < 4; tK++) {
        short8x a = *(const short8x*)(catw + tK * 32 + q4 * 8);
        acc = __builtin_amdgcn_mfma_f32_16x16x32_bf16(a, bfr[tK], acc, 0, 0, 0);
    }
    float r01 = (q4 & 1) ? acc[1] : acc[0];
    float r23 = (q4 & 1) ? acc[3] : acc[2];
    float pv  = (q4 & 2) ? r23 : r01;

    int node = bb * 4 + q4;
    float fres = dst_feat[(size_t)node * D + wid * 16 + c16];
    float oo = pv + fres;
    oo = (oo > 0.f) ? oo : (__expf(oo) - 1.f);
    outp[(size_t)node * D + wid * 16 + c16] = oo;
}

// ---------------- fallback: round-5 monolith (passed, 447us) ---------------
__global__ __launch_bounds__(256) void attn_mono(
    const float* __restrict__ src_feat, const float* __restrict__ dst_feat,
    const float* __restrict__ W_src, const float* __restrict__ W_dst,
    const float* __restrict__ Wg, const float* __restrict__ te,
    const float* __restrict__ tek, const int* __restrict__ nbr,
    const int* __restrict__ timev, float* __restrict__ out)
{
    __shared__ unsigned int ws32[64 * 33];
    __shared__ unsigned int te32[L * 33];
    __shared__ unsigned int mbs[4][L * 33];
    const int tid = threadIdx.x, lane = tid & 63, wid = tid >> 6;
    const int n = blockIdx.x * 4 + wid;
    {
        const float2* Wf2 = (const float2*)W_src;
        const float2* Te2 = (const float2*)te;
        for (int idx = tid; idx < 2048; idx += 256) {
            float2 w = Wf2[idx];
            ws32[(idx >> 5) * 33 + (idx & 31)] = packbf(w.x, w.y);
            if (idx < 1600) {
                float2 t2 = Te2[idx];
                te32[(idx >> 5) * 33 + (idx & 31)] = packbf(t2.x, t2.y);
            }
        }
    }
    __syncthreads();
    int t  = (lane < L) ? timev[(size_t)n * L + lane] : 0;
    int nb = (lane < L) ? nbr[(size_t)n * L + lane]  : 0;
    unsigned int key  = (lane < L) ? ((((unsigned)t) << 6) | (unsigned)lane) : 0u;
    unsigned int key2 = (lane < L) ? ((((unsigned)t) << 6) | (unsigned)(63 - lane)) : 0u;
    int rank = 0;
#pragma unroll
    for (int j = 0; j < L; j++) {
        unsigned int kj = (unsigned int)rli((int)key, j);
        rank += (kj < key) ? 1 : 0;
    }
    int re_o = (lane < L) ? (L - 1 - rank) : 0;
    unsigned int m2 = key2;
#pragma unroll
    for (int s = 32; s; s >>= 1) { unsigned int o2 = __shfl_xor(m2, s); m2 = (o2 > m2) ? o2 : m2; }
    const int last = 63 - (int)(m2 & 63u);
    const int rr = (lane < L) ? lane : (L - 1);
    float f = dst_feat[(size_t)n * D + lane];
    float dh;
    {
        float b0 = 0.f, b1 = 0.f, b2 = 0.f, b3 = 0.f;
#pragma unroll
        for (int k = 0; k < 64; k += 4) {
            b0 += rl(f, k + 0) * W_dst[(k + 0) * 64 + lane];
            b1 += rl(f, k + 1) * W_dst[(k + 1) * 64 + lane];
            b2 += rl(f, k + 2) * W_dst[(k + 2) * 64 + lane];
            b3 += rl(f, k + 3) * W_dst[(k + 3) * 64 + lane];
        }
        dh = (b0 + b1) + (b2 + b3);
    }
    float v1;
    {
        float b0 = 0.f, b1 = 0.f, b2 = 0.f, b3 = 0.f;
#pragma unroll
        for (int j = 0; j < 32; j += 2) {
            unsigned int u0 = ws32[lane * 33 + j];
            unsigned int u1 = ws32[lane * 33 + j + 1];
            b0 += lof(u0) * rl(dh, 2 * j + 0);
            b1 += hif(u0) * rl(dh, 2 * j + 1);
            b2 += lof(u1) * rl(dh, 2 * j + 2);
            b3 += hif(u1) * rl(dh, 2 * j + 3);
        }
        v1 = (b0 + b1) + (b2 + b3);
    }
    unsigned int* mbw = mbs[wid];
    {
        const float2* src2 = (const float2*)src_feat;
        int half = lane >> 5, col = lane & 31;
#pragma unroll
        for (int l = 0; l < L; l += 2) {
            int ra = rli(nb, l), rb = rli(nb, l + 1);
            int r = half ? rb : ra;
            float2 v = src2[(size_t)r * 32 + col];
            mbw[(l + half) * 33 + col] = packbf(v.x, v.y);
        }
    }
    __syncthreads();
    unsigned int ul = mbw[last * 33 + (lane >> 1)];
    float rlast = (lane & 1) ? hif(ul) : lof(ul);
    float g;
    {
        float b0 = 0.f, b1 = 0.f, b2 = 0.f, b3 = 0.f;
#pragma unroll
        for (int k = 0; k < 64; k += 4) {
            b0 += rl(rlast, k + 0) * W_src[(k + 0) * 64 + lane];
            b1 += rl(rlast, k + 1) * W_src[(k + 1) * 64 + lane];
            b2 += rl(rlast, k + 2) * W_src[(k + 2) * 64 + lane];
            b3 += rl(rlast, k + 3) * W_src[(k + 3) * 64 + lane];
        }
        g = (b0 + b1) + (b2 + b3);
    }
    float v2;
    {
        float b0 = 0.f, b1 = 0.f, b2 = 0.f, b3 = 0.f;
#pragma unroll
        for (int j = 0; j < 32; j += 2) {
            unsigned int u0 = ws32[lane * 33 + j];
            unsigned int u1 = ws32[lane * 33 + j + 1];
            b0 += lof(u0) * rl(g, 2 * j + 0);
            b1 += hif(u0) * rl(g, 2 * j + 1);
            b2 += lof(u1) * rl(g, 2 * j + 2);
            b3 += hif(u1) * rl(g, 2 * j + 3);
        }
        v2 = (b0 + b1) + (b2 + b3);
    }
    float teh;
    {
        float b0 = 0.f, b1 = 0.f, b2 = 0.f, b3 = 0.f;
#pragma unroll
        for (int j = 0; j < 32; j += 2) {
            unsigned int u0 = te32[rr * 33 + j];
            unsigned int u1 = te32[rr * 33 + j + 1];
            b0 += lof(u0) * rl(dh, 2 * j + 0);
            b1 += hif(u0) * rl(dh, 2 * j + 1);
            b2 += lof(u1) * rl(dh, 2 * j + 2);
            b3 += hif(u1) * rl(dh, 2 * j + 3);
        }
        teh = (b0 + b1) + (b2 + b3);
    }
    float e, e1;
    {
        float ea = 0.f, eb = 0.f, qa = 0.f, qb = 0.f;
#pragma unroll
        for (int j = 0; j < 32; j += 2) {
            unsigned int u0 = mbw[rr * 33 + j];
            unsigned int u1 = mbw[rr * 33 + j + 1];
            float m0 = lof(u0), m1 = hif(u0), m2f = lof(u1), m3 = hif(u1);
            ea += m0 * rl(v1, 2 * j + 0) + m1 * rl(v1, 2 * j + 1);
            eb += m2f * rl(v1, 2 * j + 2) + m3 * rl(v1, 2 * j + 3);
            qa += m0 * rl(v2, 2 * j + 0) + m1 * rl(v2, 2 * j + 1);
            qb += m2f * rl(v2, 2 * j + 2) + m3 * rl(v2, 2 * j + 3);
        }
        e = ea + eb; e1 = qa + qb;
    }
    e = (e + __shfl(teh, re_o)) * 0.125f;
    e1 *= 0.125f;
    if (lane >= L) { e = -3e38f; e1 = -3e38f; }
    float mx = e;
#pragma unroll
    for (int s = 32; s; s >>= 1) { float o2 = __shfl_xor(mx, s); mx = (o2 > mx) ? o2 : mx; }
    float ex = __expf(e - mx);
    float sm = ex;
#pragma unroll
    for (int s = 32; s; s >>= 1) sm += __shfl_xor(sm, s);
    float alpha = ex / sm;
    float mx1 = e1;
#pragma unroll
    for (int s = 32; s; s >>= 1) { float o2 = __shfl_xor(mx1, s); mx1 = (o2 > mx1) ? o2 : mx1; }
    float ex1 = __expf(e1 - mx1);
    float sm1 = ex1;
#pragma unroll
    for (int s = 32; s; s >>= 1) sm1 += __shfl_xor(sm1, s);
    float aw = ex1 / sm1;
    float sl, ss, tacc;
    {
        float sA = 0.f, sB = 0.f, hA = 0.f, hB = 0.f, tA = 0.f, tB = 0.f;
        int hcol = lane >> 1, odd = lane & 1;
#pragma unroll
        for (int l = 0; l < L; l += 2) {
            float saA = rl(alpha, l),     s1A = rl(aw, l);
            float saB = rl(alpha, l + 1), s1B = rl(aw, l + 1);
            int   roA = rli(re_o, l),     roB = rli(re_o, l + 1);
            unsigned int uA = mbw[(l + 0) * 33 + hcol];
            unsigned int uB = mbw[(l + 1) * 33 + hcol];
            float mA = odd ? hif(uA) : lof(uA);
            float mB = odd ? hif(uB) : lof(uB);
            sA += saA * mA; hA += s1A * mA; tA += saA * tek[roA * 64 + lane];
            sB += saB * mB; hB += s1B * mB; tB += saB * tek[roB * 64 + lane];
        }
        sl = sA + sB; ss = hA + hB; tacc = tA + tB;
    }
    float hl, hs;
    {
        float lA = 0.f, lB = 0.f, sA = 0.f, sB = 0.f;
#pragma unroll
        for (int k = 0; k < 64; k += 2) {
            float w0 = W_src[(k + 0) * 64 + lane];
            float w1 = W_src[(k + 1) * 64 + lane];
            lA += rl(sl, k + 0) * w0; sA += rl(ss, k + 0) * w0;
            lB += rl(sl, k + 1) * w1; sB += rl(ss, k + 1) * w1;
        }
        hl = tacc + lA + lB; hs = sA + sB;
    }
    float o;
    {
        float o0 = 0.f, o1 = 0.f, o2 = 0.f, o3 = 0.f;
#pragma unroll
        for (int k = 0; k < 64; k += 2) {
            o0 += rl(hl, k + 0) * Wg[(k + 0) * 64 + lane];
            o1 += rl(hl, k + 1) * Wg[(k + 1) * 64 + lane];
            o2 += rl(hs, k + 0) * Wg[(k + 64) * 64 + lane];
            o3 += rl(hs, k + 1) * Wg[(k + 65) * 64 + lane];
        }
        o = f + (o0 + o1) + (o2 + o3);
    }
    o = (o > 0.f) ? o : (__expf(o) - 1.f);
    out[(size_t)n * D + lane] = o;
}

extern "C" void kernel_launch(void* const* d_in, const int* in_sizes, int n_in,
                              void* d_out, int out_size, void* d_ws, size_t ws_size,
                              hipStream_t stream) {
    const float* user_feat = (const float*)d_in[0];
    const float* item_feat = (const float*)d_in[1];
    const float* W_u  = (const float*)d_in[2];
    const float* W_i  = (const float*)d_in[3];
    const float* Wg_u = (const float*)d_in[4];
    const float* Wg_i = (const float*)d_in[5];
    const float* i_te   = (const float*)d_in[6];
    const float* i_te_k = (const float*)d_in[7];
    const float* u_te   = (const float*)d_in[8];
    const float* u_te_k = (const float*)d_in[9];
    const int* item_nbr  = (const int*)d_in[10];
    const int* item_time = (const int*)d_in[11];
    const int* user_nbr  = (const int*)d_in[12];
    const int* user_time = (const int*)d_in[13];
    (void)in_sizes; (void)n_in; (void)out_size;

    float* outp = (float*)d_out;
    const size_t H_BYTES = (size_t)(NUM_U + NUM_I) * 32 * 4;            // 6.4 MB
    const size_t NEED = H_BYTES + 2 * 16384 + 4 * 8192;                 // +64 KB aux

    if (ws_size >= NEED) {
        unsigned int* Hp = (unsigned int*)d_ws;
        unsigned char* aux = (unsigned char*)d_ws + H_BYTES;
        unsigned short* WgPi = (unsigned short*)(aux);
        unsigned short* WgPu = (unsigned short*)(aux + 16384);
        unsigned short* tePi = (unsigned short*)(aux + 32768);
        unsigned short* tePu = (unsigned short*)(aux + 40960);
        unsigned short* tkPi = (unsigned short*)(aux + 49152);
        unsigned short* tkPu = (unsigned short*)(aux + 57344);

        prep<<<3141, 256, 0, stream>>>(user_feat, item_feat, W_u, W_i,
                                       Wg_i, Wg_u, i_te, u_te, i_te_k, u_te_k,
                                       Hp, WgPi, WgPu, tePi, tePu, tkPi, tkPu);
        attn_fused<<<(NUM_I + NUM_U) / 4, 256, 0, stream>>>(
            Hp, user_feat, item_feat, WgPi, WgPu, tePi, tePu, tkPi, tkPu,
            item_nbr, item_time, user_nbr, user_time, outp);
    } else {
        attn_mono<<<NUM_I / 4, 256, 0, stream>>>(
            user_feat, item_feat, W_u, W_i, Wg_i, i_te, i_te_k,
            item_nbr, item_time, outp + (size_t)NUM_U * D);
        attn_mono<<<NUM_U / 4, 256, 0, stream>>>(
            item_feat, user_feat, W_i, W_u, Wg_u, u_te, u_te_k,
            user_nbr, user_time, outp);
    }
}

// Round 3
// 226.960 us; speedup vs baseline: 1.2276x; 1.0403x over previous
//
#include <hip/hip_runtime.h>
#include <stdint.h>

#define D   64
#define L   50
#define NUM_U 30000
#define NUM_I 20000
#define MROWS 50
#define PW3 (MROWS * 32 + 96 + 192)   // mailbox 1600 dw | dla 96 | escf 192 = 1888 dw
#define GEMM_BLKS 782                 // 3125 row-tiles of 16, 4 waves/block

// r8: all bulk math on MFMA: 245us. r9: LDS 30.9KB, 2 dispatches: 241.5us,
//     attn=144us VALU42/Mfma8/occ53 -> VALU-issue + gather-drain bound.
// r10: dropped LDS mailbox, global gathers: 186us REGRESSED (L2-gather latency
//     on critical path). Mailbox locality is load-bearing.
// r11: DMA mailbox fill (global_load_lds w=16, chunk-XOR swizzle via
//     pre-swizzled source), b128 score reads, raw-bf16 dh/lm, setprio:
//     attn 144->137.7us. Sums u16 gathers 8-way bank-conflict (7.7M, ~2%),
//     XOR key uniform-per-instruction -> can't fix in this layout; parked.
// r12: residue arithmetic: total-attn ~= 95us stable = prep (readlane-FMA
//     GEMM, ~20x off roofline). Rewrite prep on MFMA: B-frag=feat rows
//     (float4), A-frag=W^T cols (L1 scalar), 8 mfma/wave, uint2 packed
//     stores. 3125 waves. Predict prep ~90 -> ~8us, total ~155-165us.

typedef __attribute__((ext_vector_type(8))) short short8x;   // 8 bf16
typedef __attribute__((ext_vector_type(4))) float f32x4;     // MFMA acc

__device__ __forceinline__ float lof(unsigned int u) {
    union { unsigned int i; float f; } v; v.i = u << 16; return v.f;
}
__device__ __forceinline__ float hif(unsigned int u) {
    union { unsigned int i; float f; } v; v.i = u & 0xffff0000u; return v.f;
}
__device__ __forceinline__ unsigned int f2bfbits(float f) {
    union { float f; unsigned int i; } v; v.f = f;
    return (v.i + 0x7fffu + ((v.i >> 16) & 1u)) >> 16;   // RNE
}
__device__ __forceinline__ unsigned int packbf(float a, float b) {
    return f2bfbits(a) | (f2bfbits(b) << 16);
}
__device__ __forceinline__ float rl(float v, int l) {
    return __int_as_float(__builtin_amdgcn_readlane(__float_as_int(v), l));
}
__device__ __forceinline__ int rli(int v, int l) {
    return __builtin_amdgcn_readlane(v, l);
}
__device__ __forceinline__ void gload_lds16(const void* g, void* l) {
    __builtin_amdgcn_global_load_lds(
        (const __attribute__((address_space(1))) unsigned int*)g,
        (__attribute__((address_space(3))) unsigned int*)l, 16, 0, 0);
}

// ---------------- K1: fused prep: H = feat@W (MFMA) + bf16 weight packing ---
__global__ __launch_bounds__(256) void prep(
    const float* __restrict__ user_feat, const float* __restrict__ item_feat,
    const float* __restrict__ W_u, const float* __restrict__ W_i,
    const float* __restrict__ Wg_i, const float* __restrict__ Wg_u,
    const float* __restrict__ te_i, const float* __restrict__ te_u,
    const float* __restrict__ tk_i, const float* __restrict__ tk_u,
    unsigned int* __restrict__ H,
    unsigned short* __restrict__ WgPi, unsigned short* __restrict__ WgPu,
    unsigned short* __restrict__ tePi, unsigned short* __restrict__ tePu,
    unsigned short* __restrict__ tkPi, unsigned short* __restrict__ tkPu)
{
    const int tid = threadIdx.x;
    if (blockIdx.x < GEMM_BLKS) {
        const int lane = tid & 63, wid = tid >> 6;
        const int tile = blockIdx.x * 4 + wid;            // 16 rows per tile
        if (tile >= 3125) return;                         // 3125*16 = 50000 exact
        const int r0 = tile * 16;
        const float* src; const float* W;
        if (r0 < NUM_U) { src = user_feat + (size_t)r0 * D;            W = W_u; }
        else            { src = item_feat + (size_t)(r0 - NUM_U) * D;  W = W_i; }
        const int q4 = lane >> 4, c16 = lane & 15;

        // B-frags: feat rows. B[n=c16][k=kt*32+q4*8+j], coalesced float4 pairs.
        short8x bf[2];
#pragma unroll
        for (int kt = 0; kt < 2; kt++) {
            const float* fp = src + c16 * D + kt * 32 + q4 * 8;
            float4 x = *(const float4*)fp;
            float4 y = *(const float4*)(fp + 4);
            union { short8x v; unsigned int u[4]; } t2;
            t2.u[0] = packbf(x.x, x.y); t2.u[1] = packbf(x.z, x.w);
            t2.u[2] = packbf(y.x, y.y); t2.u[3] = packbf(y.z, y.w);
            bf[kt] = t2.v;
        }
        // A-frags: W^T. A[m=c16+16mt][k] = W[k][c16+16mt]; W is 16KB, L1-hot.
        f32x4 zero4 = {0.f, 0.f, 0.f, 0.f};
        f32x4 acc[4];
#pragma unroll
        for (int mt = 0; mt < 4; mt++) acc[mt] = zero4;
#pragma unroll
        for (int kt = 0; kt < 2; kt++) {
#pragma unroll
            for (int mt = 0; mt < 4; mt++) {
                union { short8x v; unsigned short u[8]; } a;
#pragma unroll
                for (int j = 0; j < 8; j++)
                    a.u[j] = (unsigned short)f2bfbits(
                        W[(kt * 32 + q4 * 8 + j) * D + c16 + 16 * mt]);
                acc[mt] = __builtin_amdgcn_mfma_f32_16x16x32_bf16(a.v, bf[kt], acc[mt], 0, 0, 0);
            }
        }
        // D[m][n]: col(c16) = feat row n, reg row = m = q4*4+r -> H col.
        // Lane holds 4 CONSECUTIVE H cols (16mt+4q4+r): pack -> uint2 store.
        unsigned int* Hrow = H + (size_t)(r0 + c16) * 32;
#pragma unroll
        for (int mt = 0; mt < 4; mt++) {
            uint2 pk;
            pk.x = packbf(acc[mt][0], acc[mt][1]);
            pk.y = packbf(acc[mt][2], acc[mt][3]);
            *(uint2*)(Hrow + 8 * mt + 2 * q4) = pk;
        }
    } else {
        int gid = (blockIdx.x - GEMM_BLKS) * 256 + tid;   // 16 blocks, gs=4096
        for (int idx = gid; idx < 8192; idx += 4096) {
            int n = idx >> 7, k = idx & 127;
            WgPi[idx] = (unsigned short)f2bfbits(Wg_i[k * 64 + n]);
            WgPu[idx] = (unsigned short)f2bfbits(Wg_u[k * 64 + n]);
        }
        {
            int idx = gid;                                // 4096 elements, 1 iter
            int r = idx >> 6, k = idx & 63;
            tePi[idx] = (r < L) ? (unsigned short)f2bfbits(te_i[r * 64 + k]) : 0;
            tePu[idx] = (r < L) ? (unsigned short)f2bfbits(te_u[r * 64 + k]) : 0;
            int d = idx >> 6, rr = idx & 63;
            tkPi[idx] = (rr < L) ? (unsigned short)f2bfbits(tk_i[rr * 64 + d]) : 0;
            tkPu[idx] = (rr < L) ? (unsigned short)f2bfbits(tk_u[rr * 64 + d]) : 0;
        }
    }
}

// ---------------- K2: fused attention, both sides, MFMA math ----------------
__global__ __launch_bounds__(256, 5) void attn_fused(
    const unsigned int* __restrict__ H,
    const float* __restrict__ user_feat, const float* __restrict__ item_feat,
    const unsigned short* __restrict__ WgPi, const unsigned short* __restrict__ WgPu,
    const unsigned short* __restrict__ tePi, const unsigned short* __restrict__ tePu,
    const unsigned short* __restrict__ tkPi, const unsigned short* __restrict__ tkPu,
    const int* __restrict__ item_nbr, const int* __restrict__ item_time,
    const int* __restrict__ user_nbr, const int* __restrict__ user_time,
    float* __restrict__ out)
{
    __shared__ unsigned int lds[4 * PW3];   // 30208 B -> 5 blocks/CU

    const int tid = threadIdx.x, lane = tid & 63, wid = tid >> 6;
    const bool iside = blockIdx.x < (NUM_I / 4);
    const int bb = iside ? blockIdx.x : blockIdx.x - NUM_I / 4;
    const int n = bb * 4 + wid;
    const int src_base = iside ? 0 : NUM_U;
    const int dst_base = iside ? NUM_U : 0;
    const float* dst_feat = iside ? item_feat : user_feat;
    const unsigned short* WgP  = iside ? WgPi : WgPu;
    const unsigned short* teP  = iside ? tePi : tePu;
    const unsigned short* tekP = iside ? tkPi : tkPu;
    const int* nbr   = iside ? item_nbr  : user_nbr;
    const int* timev = iside ? item_time : user_time;
    float* outp = out + (iside ? (size_t)NUM_U * D : 0);

    const int q4 = lane >> 4, c16 = lane & 15;

    const unsigned int*   Hsrc = H + (size_t)src_base * 32;
    const unsigned short* Hs16 = (const unsigned short*)H + (size_t)src_base * 64;
    const unsigned short* Hd16 = (const unsigned short*)H + (size_t)dst_base * 64;

    // per-wave LDS slices
    unsigned int*   wld  = lds + wid * PW3;
    unsigned int*   mbw  = wld;                               // 50 rows x 32 dw, chunk-swizzled
    unsigned short* dla  = (unsigned short*)(wld + MROWS * 32);   // dh|lm, overlay alpha|a1|beta
    float*          escf = (float*)(wld + MROWS * 32 + 96);       // e|e1|teh (192 f32)
    unsigned short* cat  = (unsigned short*)(wld + MROWS * 32 + 96); // overlay [hl|hs]

    // ---- metadata ----
    int t   = (lane < L) ? timev[(size_t)n * L + lane] : 0;
    int nbv = (lane < L) ? nbr[(size_t)n * L + lane]  : 0;

    // ---- mailbox fill: rows 0..47 via global_load_lds (16B/lane, 8 rows/instr)
    // LDS[row][chunk c] = global[row][c ^ (row&7)]; row&7 == lane>>3 for all g
    {
        const int soff = (((lane & 7) ^ (lane >> 3)) << 4);   // swizzled src byte off
        const int rsel = (lane >> 3) << 2;                    // bpermute byte idx
#pragma unroll
        for (int g = 0; g < 6; g++) {
            int nb = __builtin_amdgcn_ds_bpermute(rsel + (g << 5), nbv);
            const char* gp = (const char*)(Hsrc + (size_t)(unsigned)nb * 32) + soff;
            gload_lds16(gp, (char*)mbw + (g << 10));
        }
        // rows 48..49: one manual pass (2 rows x 32 dw over 64 lanes)
        int row = 48 + (lane >> 5), d = lane & 31;
        int nb = __builtin_amdgcn_ds_bpermute(row << 2, nbv);
        unsigned int v = Hsrc[(size_t)(unsigned)nb * 32 + d];
        mbw[(row << 5) + ((((d >> 2) ^ (row & 7)) << 2) | (d & 3))] = v;
    }

    // ---- rank / last while DMA is in flight ----
    unsigned int key  = (lane < L) ? ((((unsigned)t) << 6) | (unsigned)lane) : 0u;
    unsigned int key2 = (lane < L) ? ((((unsigned)t) << 6) | (unsigned)(63 - lane)) : 0u;
    int rank = 0;
#pragma unroll
    for (int j = 0; j < L; j++) {
        unsigned int kj = (unsigned int)rli((int)key, j);
        rank += (kj < key) ? 1 : 0;
    }
    int re_o = (lane < L) ? (L - 1 - rank) : lane;   // pad lanes: distinct slots

    unsigned int m2 = key2;
#pragma unroll
    for (int s = 32; s; s >>= 1) { unsigned int o2 = __shfl_xor(m2, s); m2 = (o2 > m2) ? o2 : m2; }
    const int last = 63 - (int)(m2 & 63u);

    // ---- dh / lm: raw bf16 straight from H (bit-identical to f32 roundtrip)
    dla[lane] = Hd16[(size_t)n * 64 + lane];
    int nbl = __shfl(nbv, last);                      // last is wave-uniform
    dla[64 + lane] = Hs16[(size_t)(unsigned)nbl * 64 + lane];

    // ---- scores + teh via MFMA: D=[dh;lm]·M^T, D_t=[dh]·te^T ----
    f32x4 zero4 = {0.f, 0.f, 0.f, 0.f};
    f32x4 acc_e[4], acc_t[4];
#pragma unroll
    for (int nt = 0; nt < 4; nt++) { acc_e[nt] = zero4; acc_t[nt] = zero4; }
    __builtin_amdgcn_s_setprio(1);
#pragma unroll
    for (int kt = 0; kt < 2; kt++) {
        short8x afr = *(const short8x*)(dla + (c16 & 1) * 64 + kt * 32 + q4 * 8);
        int cc = kt * 4 + q4;                          // 16B chunk within row
#pragma unroll
        for (int nt = 0; nt < 4; nt++) {
            int row = c16 + 16 * nt;
            int rowc = (row < MROWS) ? row : 0;        // rows >=50 masked later
            short8x bv = *(const short8x*)((const char*)mbw + rowc * 128
                                           + ((cc ^ (rowc & 7)) << 4));
            acc_e[nt] = __builtin_amdgcn_mfma_f32_16x16x32_bf16(afr, bv, acc_e[nt], 0, 0, 0);
            short8x bt = *(const short8x*)(teP + row * 64 + kt * 32 + q4 * 8);
            acc_t[nt] = __builtin_amdgcn_mfma_f32_16x16x32_bf16(afr, bt, acc_t[nt], 0, 0, 0);
        }
    }
    __builtin_amdgcn_s_setprio(0);
    if (q4 == 0) {
#pragma unroll
        for (int nt = 0; nt < 4; nt++) {
            escf[c16 + 16 * nt]       = acc_e[nt][0];   // e
            escf[64 + c16 + 16 * nt]  = acc_e[nt][1];   // e1
            escf[128 + c16 + 16 * nt] = acc_t[nt][0];   // teh (rank-indexed)
        }
    }
    float e  = escf[lane];
    float e1 = escf[64 + lane];
    float th = escf[128 + re_o];

    e = (e + th) * 0.125f;
    e1 *= 0.125f;
    if (lane >= L) { e = -3e38f; e1 = -3e38f; }

    // ---- dual softmax over neighbors ----
    float mx = e;
#pragma unroll
    for (int s = 32; s; s >>= 1) { float o2 = __shfl_xor(mx, s); mx = (o2 > mx) ? o2 : mx; }
    float ex = __expf(e - mx);
    float sm = ex;
#pragma unroll
    for (int s = 32; s; s >>= 1) sm += __shfl_xor(sm, s);
    float alpha = ex / sm;

    float mx1 = e1;
#pragma unroll
    for (int s = 32; s; s >>= 1) { float o2 = __shfl_xor(mx1, s); mx1 = (o2 > mx1) ? o2 : mx1; }
    float ex1 = __expf(e1 - mx1);
    float sm1 = ex1;
#pragma unroll
    for (int s = 32; s; s >>= 1) sm1 += __shfl_xor(sm1, s);
    float aw = ex1 / sm1;

    // ---- alpha/a1/beta (bf16) overlay onto dla (dh/lm dead after scores) ----
    // pad lanes: alpha == aw == 0 exactly -> rows >=50 contribute nothing below
    dla[lane]       = (unsigned short)f2bfbits(alpha);
    dla[64 + lane]  = (unsigned short)f2bfbits(aw);
    dla[128 + re_o] = (unsigned short)f2bfbits(alpha);   // beta[r]: alpha at rank r

    // ---- sums via MFMA: [alpha;a1]·M (swizzled u16 col-reads) + [beta]·tek^T
    f32x4 acc_s[4], acc_k[4];
#pragma unroll
    for (int nt = 0; nt < 4; nt++) { acc_s[nt] = zero4; acc_k[nt] = zero4; }
    __builtin_amdgcn_s_setprio(1);
#pragma unroll
    for (int kt = 0; kt < 2; kt++) {
        short8x aS = *(const short8x*)(dla + (c16 & 1) * 64 + kt * 32 + q4 * 8);
        short8x aB = *(const short8x*)(dla + 128 + kt * 32 + q4 * 8);
        int kr128[8];
#pragma unroll
        for (int i = 0; i < 8; i++) {
            int k = kt * 32 + q4 * 8 + i;
            if (kt) k = (k < MROWS) ? k : (k - 32);   // alpha=0 rows: any finite row
            kr128[i] = k << 7;                        // preserves k&7 == i
        }
#pragma unroll
        for (int nt = 0; nt < 4; nt++) {
            int dc = c16 + 16 * nt;
            int t3 = dc >> 3;
            const char* cbase = (const char*)mbw + ((dc & 7) << 1);
            union { short8x v; unsigned short u[8]; } bu;
#pragma unroll
            for (int i = 0; i < 8; i++)
                bu.u[i] = *(const unsigned short*)(cbase + kr128[i] + ((t3 ^ i) << 4));
            acc_s[nt] = __builtin_amdgcn_mfma_f32_16x16x32_bf16(aS, bu.v, acc_s[nt], 0, 0, 0);
            short8x bK = *(const short8x*)(tekP + dc * 64 + kt * 32 + q4 * 8);
            acc_k[nt] = __builtin_amdgcn_mfma_f32_16x16x32_bf16(aB, bK, acc_k[nt], 0, 0, 0);
        }
    }
    __builtin_amdgcn_s_setprio(0);
    // cat = [hl|hs] overlay onto escf (dead after softmax)
    if (q4 == 0) {
#pragma unroll
        for (int nt = 0; nt < 4; nt++) {
            cat[c16 + 16 * nt]      = (unsigned short)f2bfbits(acc_s[nt][0] + acc_k[nt][0]);
            cat[64 + c16 + 16 * nt] = (unsigned short)f2bfbits(acc_s[nt][1]);
        }
    }
    __syncthreads();   // only barrier: epilogue mixes waves' cat rows

    // ---- epilogue: out = elu(cat @ Wg + f) ----
    short8x bfr[4];
#pragma unroll
    for (int tK = 0; tK < 4; tK++)
        bfr[tK] = *(const short8x*)(WgP + (wid * 16 + c16) * 128 + tK * 32 + q4 * 8);

    const unsigned short* catw =
        (const unsigned short*)(lds + (lane & 3) * PW3 + MROWS * 32 + 96);
    f32x4 acc = zero4;
#pragma unroll
    for (int tK = 0; tK < 4; tK++) {
        short8x a = *(const short8x*)(catw + tK * 32 + q4 * 8);
        acc = __builtin_amdgcn_mfma_f32_16x16x32_bf16(a, bfr[tK], acc, 0, 0, 0);
    }
    float r01 = (q4 & 1) ? acc[1] : acc[0];
    float r23 = (q4 & 1) ? acc[3] : acc[2];
    float pv  = (q4 & 2) ? r23 : r01;

    int node = bb * 4 + q4;
    float fres = dst_feat[(size_t)node * D + wid * 16 + c16];
    float oo = pv + fres;
    oo = (oo > 0.f) ? oo : (__expf(oo) - 1.f);
    outp[(size_t)node * D + wid * 16 + c16] = oo;
}

// ---------------- fallback: round-5 monolith (passed, 447us) ---------------
__global__ __launch_bounds__(256) void attn_mono(
    const float* __restrict__ src_feat, const float* __restrict__ dst_feat,
    const float* __restrict__ W_src, const float* __restrict__ W_dst,
    const float* __restrict__ Wg, const float* __restrict__ te,
    const float* __restrict__ tek, const int* __restrict__ nbr,
    const int* __restrict__ timev, float* __restrict__ out)
{
    __shared__ unsigned int ws32[64 * 33];
    __shared__ unsigned int te32[L * 33];
    __shared__ unsigned int mbs[4][L * 33];
    const int tid = threadIdx.x, lane = tid & 63, wid = tid >> 6;
    const int n = blockIdx.x * 4 + wid;
    {
        const float2* Wf2 = (const float2*)W_src;
        const float2* Te2 = (const float2*)te;
        for (int idx = tid; idx < 2048; idx += 256) {
            float2 w = Wf2[idx];
            ws32[(idx >> 5) * 33 + (idx & 31)] = packbf(w.x, w.y);
            if (idx < 1600) {
                float2 t2 = Te2[idx];
                te32[(idx >> 5) * 33 + (idx & 31)] = packbf(t2.x, t2.y);
            }
        }
    }
    __syncthreads();
    int t  = (lane < L) ? timev[(size_t)n * L + lane] : 0;
    int nb = (lane < L) ? nbr[(size_t)n * L + lane]  : 0;
    unsigned int key  = (lane < L) ? ((((unsigned)t) << 6) | (unsigned)lane) : 0u;
    unsigned int key2 = (lane < L) ? ((((unsigned)t) << 6) | (unsigned)(63 - lane)) : 0u;
    int rank = 0;
#pragma unroll
    for (int j = 0; j < L; j++) {
        unsigned int kj = (unsigned int)rli((int)key, j);
        rank += (kj < key) ? 1 : 0;
    }
    int re_o = (lane < L) ? (L - 1 - rank) : 0;
    unsigned int m2 = key2;
#pragma unroll
    for (int s = 32; s; s >>= 1) { unsigned int o2 = __shfl_xor(m2, s); m2 = (o2 > m2) ? o2 : m2; }
    const int last = 63 - (int)(m2 & 63u);
    const int rr = (lane < L) ? lane : (L - 1);
    float f = dst_feat[(size_t)n * D + lane];
    float dh;
    {
        float b0 = 0.f, b1 = 0.f, b2 = 0.f, b3 = 0.f;
#pragma unroll
        for (int k = 0; k < 64; k += 4) {
            b0 += rl(f, k + 0) * W_dst[(k + 0) * 64 + lane];
            b1 += rl(f, k + 1) * W_dst[(k + 1) * 64 + lane];
            b2 += rl(f, k + 2) * W_dst[(k + 2) * 64 + lane];
            b3 += rl(f, k + 3) * W_dst[(k + 3) * 64 + lane];
        }
        dh = (b0 + b1) + (b2 + b3);
    }
    float v1;
    {
        float b0 = 0.f, b1 = 0.f, b2 = 0.f, b3 = 0.f;
#pragma unroll
        for (int j = 0; j < 32; j += 2) {
            unsigned int u0 = ws32[lane * 33 + j];
            unsigned int u1 = ws32[lane * 33 + j + 1];
            b0 += lof(u0) * rl(dh, 2 * j + 0);
            b1 += hif(u0) * rl(dh, 2 * j + 1);
            b2 += lof(u1) * rl(dh, 2 * j + 2);
            b3 += hif(u1) * rl(dh, 2 * j + 3);
        }
        v1 = (b0 + b1) + (b2 + b3);
    }
    unsigned int* mbw = mbs[wid];
    {
        const float2* src2 = (const float2*)src_feat;
        int half = lane >> 5, col = lane & 31;
#pragma unroll
        for (int l = 0; l < L; l += 2) {
            int ra = rli(nb, l), rb = rli(nb, l + 1);
            int r = half ? rb : ra;
            float2 v = src2[(size_t)r * 32 + col];
            mbw[(l + half) * 33 + col] = packbf(v.x, v.y);
        }
    }
    __syncthreads();
    unsigned int ul = mbw[last * 33 + (lane >> 1)];
    float rlast = (lane & 1) ? hif(ul) : lof(ul);
    float g;
    {
        float b0 = 0.f, b1 = 0.f, b2 = 0.f, b3 = 0.f;
#pragma unroll
        for (int k = 0; k < 64; k += 4) {
            b0 += rl(rlast, k + 0) * W_src[(k + 0) * 64 + lane];
            b1 += rl(rlast, k + 1) * W_src[(k + 1) * 64 + lane];
            b2 += rl(rlast, k + 2) * W_src[(k + 2) * 64 + lane];
            b3 += rl(rlast, k + 3) * W_src[(k + 3) * 64 + lane];
        }
        g = (b0 + b1) + (b2 + b3);
    }
    float v2;
    {
        float b0 = 0.f, b1 = 0.f, b2 = 0.f, b3 = 0.f;
#pragma unroll
        for (int j = 0; j < 32; j += 2) {
            unsigned int u0 = ws32[lane * 33 + j];
            unsigned int u1 = ws32[lane * 33 + j + 1];
            b0 += lof(u0) * rl(g, 2 * j + 0);
            b1 += hif(u0) * rl(g, 2 * j + 1);
            b2 += lof(u1) * rl(g, 2 * j + 2);
            b3 += hif(u1) * rl(g, 2 * j + 3);
        }
        v2 = (b0 + b1) + (b2 + b3);
    }
    float teh;
    {
        float b0 = 0.f, b1 = 0.f, b2 = 0.f, b3 = 0.f;
#pragma unroll
        for (int j = 0; j < 32; j += 2) {
            unsigned int u0 = te32[rr * 33 + j];
            unsigned int u1 = te32[rr * 33 + j + 1];
            b0 += lof(u0) * rl(dh, 2 * j + 0);
            b1 += hif(u0) * rl(dh, 2 * j + 1);
            b2 += lof(u1) * rl(dh, 2 * j + 2);
            b3 += hif(u1) * rl(dh, 2 * j + 3);
        }
        teh = (b0 + b1) + (b2 + b3);
    }
    float e, e1;
    {
        float ea = 0.f, eb = 0.f, qa = 0.f, qb = 0.f;
#pragma unroll
        for (int j = 0; j < 32; j += 2) {
            unsigned int u0 = mbw[rr * 33 + j];
            unsigned int u1 = mbw[rr * 33 + j + 1];
            float m0 = lof(u0), m1 = hif(u0), m2f = lof(u1), m3 = hif(u1);
            ea += m0 * rl(v1, 2 * j + 0) + m1 * rl(v1, 2 * j + 1);
            eb += m2f * rl(v1, 2 * j + 2) + m3 * rl(v1, 2 * j + 3);
            qa += m0 * rl(v2, 2 * j + 0) + m1 * rl(v2, 2 * j + 1);
            qb += m2f * rl(v2, 2 * j + 2) + m3 * rl(v2, 2 * j + 3);
        }
        e = ea + eb; e1 = qa + qb;
    }
    e = (e + __shfl(teh, re_o)) * 0.125f;
    e1 *= 0.125f;
    if (lane >= L) { e = -3e38f; e1 = -3e38f; }
    float mx = e;
#pragma unroll
    for (int s = 32; s; s >>= 1) { float o2 = __shfl_xor(mx, s); mx = (o2 > mx) ? o2 : mx; }
    float ex = __expf(e - mx);
    float sm = ex;
#pragma unroll
    for (int s = 32; s; s >>= 1) sm += __shfl_xor(sm, s);
    float alpha = ex / sm;
    float mx1 = e1;
#pragma unroll
    for (int s = 32; s; s >>= 1) { float o2 = __shfl_xor(mx1, s); mx1 = (o2 > mx1) ? o2 : mx1; }
    float ex1 = __expf(e1 - mx1);
    float sm1 = ex1;
#pragma unroll
    for (int s = 32; s; s >>= 1) sm1 += __shfl_xor(sm1, s);
    float aw = ex1 / sm1;
    float sl, ss, tacc;
    {
        float sA = 0.f, sB = 0.f, hA = 0.f, hB = 0.f, tA = 0.f, tB = 0.f;
        int hcol = lane >> 1, odd = lane & 1;
#pragma unroll
        for (int l = 0; l < L; l += 2) {
            float saA = rl(alpha, l),     s1A = rl(aw, l);
            float saB = rl(alpha, l + 1), s1B = rl(aw, l + 1);
            int   roA = rli(re_o, l),     roB = rli(re_o, l + 1);
            unsigned int uA = mbw[(l + 0) * 33 + hcol];
            unsigned int uB = mbw[(l + 1) * 33 + hcol];
            float mA = odd ? hif(uA) : lof(uA);
            float mB = odd ? hif(uB) : lof(uB);
            sA += saA * mA; hA += s1A * mA; tA += saA * tek[roA * 64 + lane];
            sB += saB * mB; hB += s1B * mB; tB += saB * tek[roB * 64 + lane];
        }
        sl = sA + sB; ss = hA + hB; tacc = tA + tB;
    }
    float hl, hs;
    {
        float lA = 0.f, lB = 0.f, sA = 0.f, sB = 0.f;
#pragma unroll
        for (int k = 0; k < 64; k += 2) {
            float w0 = W_src[(k + 0) * 64 + lane];
            float w1 = W_src[(k + 1) * 64 + lane];
            lA += rl(sl, k + 0) * w0; sA += rl(ss, k + 0) * w0;
            lB += rl(sl, k + 1) * w1; sB += rl(ss, k + 1) * w1;
        }
        hl = tacc + lA + lB; hs = sA + sB;
    }
    float o;
    {
        float o0 = 0.f, o1 = 0.f, o2 = 0.f, o3 = 0.f;
#pragma unroll
        for (int k = 0; k < 64; k += 2) {
            o0 += rl(hl, k + 0) * Wg[(k + 0) * 64 + lane];
            o1 += rl(hl, k + 1) * Wg[(k + 1) * 64 + lane];
            o2 += rl(hs, k + 0) * Wg[(k + 64) * 64 + lane];
            o3 += rl(hs, k + 1) * Wg[(k + 65) * 64 + lane];
        }
        o = f + (o0 + o1) + (o2 + o3);
    }
    o = (o > 0.f) ? o : (__expf(o) - 1.f);
    out[(size_t)n * D + lane] = o;
}

extern "C" void kernel_launch(void* const* d_in, const int* in_sizes, int n_in,
                              void* d_out, int out_size, void* d_ws, size_t ws_size,
                              hipStream_t stream) {
    const float* user_feat = (const float*)d_in[0];
    const float* item_feat = (const float*)d_in[1];
    const float* W_u  = (const float*)d_in[2];
    const float* W_i  = (const float*)d_in[3];
    const float* Wg_u = (const float*)d_in[4];
    const float* Wg_i = (const float*)d_in[5];
    const float* i_te   = (const float*)d_in[6];
    const float* i_te_k = (const float*)d_in[7];
    const float* u_te   = (const float*)d_in[8];
    const float* u_te_k = (const float*)d_in[9];
    const int* item_nbr  = (const int*)d_in[10];
    const int* item_time = (const int*)d_in[11];
    const int* user_nbr  = (const int*)d_in[12];
    const int* user_time = (const int*)d_in[13];
    (void)in_sizes; (void)n_in; (void)out_size;

    float* outp = (float*)d_out;
    const size_t H_BYTES = (size_t)(NUM_U + NUM_I) * 32 * 4;            // 6.4 MB
    const size_t NEED = H_BYTES + 2 * 16384 + 4 * 8192;                 // +64 KB aux

    if (ws_size >= NEED) {
        unsigned int* Hp = (unsigned int*)d_ws;
        unsigned char* aux = (unsigned char*)d_ws + H_BYTES;
        unsigned short* WgPi = (unsigned short*)(aux);
        unsigned short* WgPu = (unsigned short*)(aux + 16384);
        unsigned short* tePi = (unsigned short*)(aux + 32768);
        unsigned short* tePu = (unsigned short*)(aux + 40960);
        unsigned short* tkPi = (unsigned short*)(aux + 49152);
        unsigned short* tkPu = (unsigned short*)(aux + 57344);

        prep<<<GEMM_BLKS + 16, 256, 0, stream>>>(user_feat, item_feat, W_u, W_i,
                                       Wg_i, Wg_u, i_te, u_te, i_te_k, u_te_k,
                                       Hp, WgPi, WgPu, tePi, tePu, tkPi, tkPu);
        attn_fused<<<(NUM_I + NUM_U) / 4, 256, 0, stream>>>(
            Hp, user_feat, item_feat, WgPi, WgPu, tePi, tePu, tkPi, tkPu,
            item_nbr, item_time, user_nbr, user_time, outp);
    } else {
        attn_mono<<<NUM_I / 4, 256, 0, stream>>>(
            user_feat, item_feat, W_u, W_i, Wg_i, i_te, i_te_k,
            item_nbr, item_time, outp + (size_t)NUM_U * D);
        attn_mono<<<NUM_U / 4, 256, 0, stream>>>(
            item_feat, user_feat, W_i, W_u, Wg_u, u_te, u_te_k,
            user_nbr, user_time, outp);
    }
}